// Round 4
// baseline (41.114 us; speedup 1.0000x reference)
//
#include <hip/hip_runtime.h>

// LBP fused kernel: RGB->gray -> 3x3 binary-compare sum s -> 3x3 weighted LBP sum.
// One pass over HBM: in 100.7MB read + 33.5MB write.
//
// Gray is computed in f32 with an explicit FMA chain:
//   gray = fma(b, w2, fma(g, w1, r*w0))
// matching OpenBLAS sgemv_t's accumulation (np.tensordot -> BLAS) which the
// harness's numpy reference uses. R2 (plain f32 mul/add) and R3 (exact f64)
// both failed with identical absmax=128 -- the signature of near-tie compare
// flips against an FMA-rounded reference gray.
//
// Tile 64x64 per block (256 threads). LDS: gray 68x68 + s 66x66 (f32, 36KB).
// Zero padding outside the 512x512 image matches jnp.pad for BOTH stages.

#define TILE 64
#define TPB  256
#define GDIM 68   // TILE + 4 (gray halo 2 each side)
#define SDIM 66   // TILE + 2 (s halo 1 each side)

__global__ __launch_bounds__(TPB) void lbp_kernel(const float* __restrict__ in,
                                                  float* __restrict__ out) {
    __shared__ float grayS[GDIM * GDIM];
    __shared__ float sS[SDIM * SDIM];

    const int n  = blockIdx.z;
    const int y0 = blockIdx.y * TILE;
    const int x0 = blockIdx.x * TILE;
    const int tid = threadIdx.x;

    // ---- Phase 1: gray tile with halo 2, zero outside image ----
    for (int i = tid; i < GDIM * GDIM; i += TPB) {
        const int ly = i / GDIM;
        const int lx = i - ly * GDIM;
        const int gy = y0 - 2 + ly;
        const int gx = x0 - 2 + lx;
        float g = 0.0f;
        if ((unsigned)gy < 512u && (unsigned)gx < 512u) {
            const float* p = in + ((size_t)(n * 512 + gy) * 512 + (size_t)gx) * 3;
            // FMA chain matching BLAS sgemv accumulation:
            g = __builtin_fmaf(p[2], 0.114f,
                __builtin_fmaf(p[1], 0.587f, p[0] * 0.2989f));
        }
        grayS[i] = g;
    }
    __syncthreads();

    // ---- Phase 2: s = sum of (neighbor >= center) over 3x3, halo 1 ----
    for (int i = tid; i < SDIM * SDIM; i += TPB) {
        const int ly = i / SDIM;
        const int lx = i - ly * SDIM;
        const int yy = y0 - 1 + ly;
        const int xx = x0 - 1 + lx;
        float s = 0.0f;
        if ((unsigned)yy < 512u && (unsigned)xx < 512u) {
            const float c = grayS[(ly + 1) * GDIM + (lx + 1)];
            #pragma unroll
            for (int dy = 0; dy < 3; ++dy) {
                #pragma unroll
                for (int dx = 0; dx < 3; ++dx) {
                    s += (grayS[(ly + dy) * GDIM + (lx + dx)] >= c) ? 1.0f : 0.0f;
                }
            }
        }
        sS[i] = s;
    }
    __syncthreads();

    // ---- Phase 3: LBP = cross-correlation of s with K, K[1][1]=0 ----
    // K = [[1,2,4],[128,0,8],[64,32,16]]; sS row 0 corresponds to y0-1.
    const int tx = tid & 63;
    const int ty = tid >> 6;  // 0..3
    #pragma unroll
    for (int r = 0; r < 16; ++r) {
        const int py = r * 4 + ty;
        const int px = tx;
        const float* s0 = &sS[(py + 0) * SDIM + px];
        const float* s1 = &sS[(py + 1) * SDIM + px];
        const float* s2 = &sS[(py + 2) * SDIM + px];
        // Integer-valued fp32 values; sums are exact regardless of order.
        float acc =   1.0f * s0[0] +   2.0f * s0[1] +  4.0f * s0[2]
                  + 128.0f * s1[0] +                    8.0f * s1[2]
                  +  64.0f * s2[0] +  32.0f * s2[1] + 16.0f * s2[2];
        out[(size_t)(n * 512 + (y0 + py)) * 512 + (size_t)(x0 + px)] = acc;
    }
}

extern "C" void kernel_launch(void* const* d_in, const int* in_sizes, int n_in,
                              void* d_out, int out_size, void* d_ws, size_t ws_size,
                              hipStream_t stream) {
    const float* in = (const float*)d_in[0];
    float* out = (float*)d_out;
    dim3 grid(512 / TILE, 512 / TILE, 32);  // 8 x 8 x 32 = 2048 blocks
    dim3 block(TPB);
    lbp_kernel<<<grid, block, 0, stream>>>(in, out);
}

// Round 5
// 36.634 us; speedup vs baseline: 1.1223x; 1.1223x over previous
//
#include <hip/hip_runtime.h>

// LBP fused kernel: RGB->gray -> 3x3 binary-compare sum s -> 3x3 weighted LBP.
// Gray uses the exact FMA chain fma(b,.114, fma(g,.587, r*.2989)) -- bit-match
// with the harness's numpy (BLAS sgemv) reference; DO NOT change the formula.
//
// R4 was latency-bound: 38% occupancy (36KB LDS -> 4 blocks/CU), 14% HBM BW,
// 27% VALU. This round: 64x32 tile -> 18.3KB LDS -> 8 blocks/CU (wave-capped,
// 100% occupancy), 4096 blocks, branchless clamped loads (no divergence, full
// load pipelining).

#define TILE_X 64
#define TILE_Y 32
#define TPB    256
#define GROWS  36   // TILE_Y + 4
#define GCOLS  68   // TILE_X + 4
#define SROWS  34   // TILE_Y + 2
#define SCOLS  66   // TILE_X + 2

__global__ __launch_bounds__(TPB) void lbp_kernel(const float* __restrict__ in,
                                                  float* __restrict__ out) {
    __shared__ float grayS[GROWS * GCOLS];
    __shared__ float sS[SROWS * SCOLS];

    const int n  = blockIdx.z;
    const int y0 = blockIdx.y * TILE_Y;
    const int x0 = blockIdx.x * TILE_X;
    const int tid = threadIdx.x;

    // ---- Phase 1: gray tile with halo 2; branchless zero outside image ----
    #pragma unroll
    for (int k = 0; k < (GROWS * GCOLS + TPB - 1) / TPB; ++k) {
        const int i = tid + k * TPB;
        if (i < GROWS * GCOLS) {
            const int ly = i / GCOLS;
            const int lx = i - ly * GCOLS;
            const int gy = y0 - 2 + ly;
            const int gx = x0 - 2 + lx;
            const bool ok = ((unsigned)gy < 512u) & ((unsigned)gx < 512u);
            const int cy = min(max(gy, 0), 511);
            const int cx = min(max(gx, 0), 511);
            const float* p = in + ((size_t)(n * 512 + cy) * 512 + (size_t)cx) * 3;
            // Exact FMA chain matching BLAS sgemv accumulation (bit-exact req).
            const float g = __builtin_fmaf(p[2], 0.114f,
                            __builtin_fmaf(p[1], 0.587f, p[0] * 0.2989f));
            grayS[i] = ok ? g : 0.0f;
        }
    }
    __syncthreads();

    // ---- Phase 2: s = sum of (neighbor >= center), halo 1, branchless ----
    #pragma unroll
    for (int k = 0; k < (SROWS * SCOLS + TPB - 1) / TPB; ++k) {
        const int i = tid + k * TPB;
        if (i < SROWS * SCOLS) {
            const int ly = i / SCOLS;
            const int lx = i - ly * SCOLS;
            const float c = grayS[(ly + 1) * GCOLS + (lx + 1)];
            float s = 0.0f;
            #pragma unroll
            for (int dy = 0; dy < 3; ++dy) {
                #pragma unroll
                for (int dx = 0; dx < 3; ++dx) {
                    s += (grayS[(ly + dy) * GCOLS + (lx + dx)] >= c) ? 1.0f : 0.0f;
                }
            }
            const bool ok = ((unsigned)(y0 - 1 + ly) < 512u) &
                            ((unsigned)(x0 - 1 + lx) < 512u);
            sS[i] = ok ? s : 0.0f;
        }
    }
    __syncthreads();

    // ---- Phase 3: LBP = cross-correlation of s with K, K[1][1]=0 ----
    // K = [[1,2,4],[128,0,8],[64,32,16]]; sS row 0 corresponds to y0-1.
    const int tx = tid & 63;
    const int ty = tid >> 6;  // 0..3
    #pragma unroll
    for (int r = 0; r < TILE_Y / 4; ++r) {
        const int py = r * 4 + ty;
        const int px = tx;
        const float* s0 = &sS[(py + 0) * SCOLS + px];
        const float* s1 = &sS[(py + 1) * SCOLS + px];
        const float* s2 = &sS[(py + 2) * SCOLS + px];
        // Integer-valued fp32; sums exact regardless of order.
        const float acc =   1.0f * s0[0] +   2.0f * s0[1] +  4.0f * s0[2]
                        + 128.0f * s1[0] +                    8.0f * s1[2]
                        +  64.0f * s2[0] +  32.0f * s2[1] + 16.0f * s2[2];
        out[(size_t)(n * 512 + (y0 + py)) * 512 + (size_t)(x0 + px)] = acc;
    }
}

extern "C" void kernel_launch(void* const* d_in, const int* in_sizes, int n_in,
                              void* d_out, int out_size, void* d_ws, size_t ws_size,
                              hipStream_t stream) {
    const float* in = (const float*)d_in[0];
    float* out = (float*)d_out;
    dim3 grid(512 / TILE_X, 512 / TILE_Y, 32);  // 8 x 16 x 32 = 4096 blocks
    dim3 block(TPB);
    lbp_kernel<<<grid, block, 0, stream>>>(in, out);
}

// Round 7
// 31.335 us; speedup vs baseline: 1.3121x; 1.1691x over previous
//
#include <hip/hip_runtime.h>

// LBP fused kernel: RGB->gray -> 3x3 binary-compare sum s -> 3x3 weighted LBP.
// Gray uses the exact FMA chain fma(b,.114, fma(g,.587, r*.2989)) -- bit-match
// with the harness's numpy (BLAS sgemv) reference; DO NOT change the formula.
//
// R5 was still latency/instruction-bound (36.6us vs ~18us floor). This round:
// everything vectorized to 16B. Phase1: 4 pixels/thread via 3 aligned
// global_load_dwordx4 (gray tile widened to 72 cols so quads start at x%4==0;
// quads are fully in- or out-of-image in x since 512%4==0). Phase2/3: 4
// outputs/thread via 6 ds_read_b128 + 1 float4 write. Output stores are
// nontemporal (write-once data; keep input in L3).
//
// R6 fix: __builtin_nontemporal_store needs a NATIVE vector type, not HIP's
// float4 class -> use ext_vector_type(4).

#define TPB    256
#define TILE_X 64
#define TILE_Y 32
#define GROWS  36   // y0-2 .. y0+33
#define GCOLS  72   // x0-4 .. x0+67 (image x); col c <-> image x = x0-4+c
#define SROWS  34   // s row r <-> image y = y0-1+r
#define SCOLS  68   // s col c <-> image x = x0-1+c; cols 0..65 used, 68 for alignment

typedef float f32x4 __attribute__((ext_vector_type(4)));

__global__ __launch_bounds__(TPB) void lbp_kernel(const float* __restrict__ in,
                                                  float* __restrict__ out) {
    __shared__ float grayS[GROWS * GCOLS];  // 10368 B
    __shared__ float sS[SROWS * SCOLS];     //  9248 B

    const int n   = blockIdx.z;
    const int y0  = blockIdx.y * TILE_Y;
    const int x0  = blockIdx.x * TILE_X;
    const int tid = threadIdx.x;

    // ---- Phase 1: gray tile, 4-pixel quads, 3x float4 loads each ----
    // 36 rows x 18 quads = 648 quads.
    #pragma unroll
    for (int k = 0; k < 3; ++k) {
        const int i = tid + k * TPB;
        if (i < GROWS * (GCOLS / 4)) {
            const int qy  = i / (GCOLS / 4);
            const int qx  = i - qy * (GCOLS / 4);
            const int gy  = y0 - 2 + qy;
            const int px0 = x0 - 4 + qx * 4;           // multiple of 4
            const bool oky = (unsigned)gy  < 512u;
            const bool okx = (unsigned)px0 < 512u;     // quad fully in or out
            const int  cy  = min(max(gy, 0), 511);
            const int  cx  = okx ? px0 : 0;
            const f32x4* p4 = reinterpret_cast<const f32x4*>(
                in + ((size_t)(n * 512 + cy) * 512 + (size_t)cx) * 3);
            const f32x4 f0 = p4[0];   // p0.r p0.g p0.b p1.r
            const f32x4 f1 = p4[1];   // p1.g p1.b p2.r p2.g
            const f32x4 f2 = p4[2];   // p2.b p3.r p3.g p3.b
            const bool ok = okx & oky;
            // Exact FMA chain matching BLAS sgemv accumulation (bit-exact req).
            const float g0 = __builtin_fmaf(f0.z, 0.114f, __builtin_fmaf(f0.y, 0.587f, f0.x * 0.2989f));
            const float g1 = __builtin_fmaf(f1.y, 0.114f, __builtin_fmaf(f1.x, 0.587f, f0.w * 0.2989f));
            const float g2 = __builtin_fmaf(f2.x, 0.114f, __builtin_fmaf(f1.w, 0.587f, f1.z * 0.2989f));
            const float g3 = __builtin_fmaf(f2.w, 0.114f, __builtin_fmaf(f2.z, 0.587f, f2.y * 0.2989f));
            f32x4 gv;
            gv.x = ok ? g0 : 0.0f;
            gv.y = ok ? g1 : 0.0f;
            gv.z = ok ? g2 : 0.0f;
            gv.w = ok ? g3 : 0.0f;
            *reinterpret_cast<f32x4*>(&grayS[qy * GCOLS + qx * 4]) = gv;
        }
    }
    __syncthreads();

    // ---- Phase 2: s (compare-sum), 4 pixels/thread, 6x ds_read_b128 ----
    // s pixel (ly,lx): image (y0-1+ly, x0-1+lx); gray window cols lx+2..lx+4,
    // rows ly..ly+2; center (ly+1, lx+3). 34 rows x 17 quads = 578 quads.
    #pragma unroll
    for (int k = 0; k < 3; ++k) {
        const int i = tid + k * TPB;
        if (i < SROWS * (SCOLS / 4)) {
            const int ly  = i / (SCOLS / 4);
            const int lx0 = (i - ly * (SCOLS / 4)) * 4;
            const f32x4 a0 = *reinterpret_cast<const f32x4*>(&grayS[(ly + 0) * GCOLS + lx0]);
            const f32x4 b0 = *reinterpret_cast<const f32x4*>(&grayS[(ly + 0) * GCOLS + lx0 + 4]);
            const f32x4 a1 = *reinterpret_cast<const f32x4*>(&grayS[(ly + 1) * GCOLS + lx0]);
            const f32x4 b1 = *reinterpret_cast<const f32x4*>(&grayS[(ly + 1) * GCOLS + lx0 + 4]);
            const f32x4 a2 = *reinterpret_cast<const f32x4*>(&grayS[(ly + 2) * GCOLS + lx0]);
            const f32x4 b2 = *reinterpret_cast<const f32x4*>(&grayS[(ly + 2) * GCOLS + lx0 + 4]);
            const float r0[8] = {a0.x, a0.y, a0.z, a0.w, b0.x, b0.y, b0.z, b0.w};
            const float r1[8] = {a1.x, a1.y, a1.z, a1.w, b1.x, b1.y, b1.z, b1.w};
            const float r2[8] = {a2.x, a2.y, a2.z, a2.w, b2.x, b2.y, b2.z, b2.w};
            float sv[4];
            #pragma unroll
            for (int e = 0; e < 4; ++e) {
                const float c = r1[3 + e];
                float s = 0.0f;
                #pragma unroll
                for (int d = 0; d < 3; ++d) {
                    s += (r0[2 + e + d] >= c) ? 1.0f : 0.0f;
                    s += (r1[2 + e + d] >= c) ? 1.0f : 0.0f;
                    s += (r2[2 + e + d] >= c) ? 1.0f : 0.0f;
                }
                const bool ok = ((unsigned)(y0 - 1 + ly) < 512u) &
                                ((unsigned)(x0 - 1 + lx0 + e) < 512u);
                sv[e] = ok ? s : 0.0f;
            }
            f32x4 svv;
            svv.x = sv[0]; svv.y = sv[1]; svv.z = sv[2]; svv.w = sv[3];
            *reinterpret_cast<f32x4*>(&sS[ly * SCOLS + lx0]) = svv;
        }
    }
    __syncthreads();

    // ---- Phase 3: LBP cross-correlation, 4 outputs/thread ----
    // K = [[1,2,4],[128,0,8],[64,32,16]]; output (py,px) uses s rows py..py+2,
    // cols px..px+2. 32 rows x 16 quads = 512 quads = exactly 2 iterations.
    #pragma unroll
    for (int k = 0; k < 2; ++k) {
        const int i   = tid + k * TPB;
        const int py  = i / (TILE_X / 4);
        const int px0 = (i - py * (TILE_X / 4)) * 4;
        const f32x4 a0 = *reinterpret_cast<const f32x4*>(&sS[(py + 0) * SCOLS + px0]);
        const f32x4 b0 = *reinterpret_cast<const f32x4*>(&sS[(py + 0) * SCOLS + px0 + 4]);
        const f32x4 a1 = *reinterpret_cast<const f32x4*>(&sS[(py + 1) * SCOLS + px0]);
        const f32x4 b1 = *reinterpret_cast<const f32x4*>(&sS[(py + 1) * SCOLS + px0 + 4]);
        const f32x4 a2 = *reinterpret_cast<const f32x4*>(&sS[(py + 2) * SCOLS + px0]);
        const f32x4 b2 = *reinterpret_cast<const f32x4*>(&sS[(py + 2) * SCOLS + px0 + 4]);
        const float r0[8] = {a0.x, a0.y, a0.z, a0.w, b0.x, b0.y, b0.z, b0.w};
        const float r1[8] = {a1.x, a1.y, a1.z, a1.w, b1.x, b1.y, b1.z, b1.w};
        const float r2[8] = {a2.x, a2.y, a2.z, a2.w, b2.x, b2.y, b2.z, b2.w};
        f32x4 ov;
        #pragma unroll
        for (int e = 0; e < 4; ++e) {
            // Integer-valued fp32; sums exact regardless of order.
            ov[e] =   1.0f * r0[e] +   2.0f * r0[e + 1] +  4.0f * r0[e + 2]
                  + 128.0f * r1[e] +                        8.0f * r1[e + 2]
                  +  64.0f * r2[e] +  32.0f * r2[e + 1] + 16.0f * r2[e + 2];
        }
        f32x4* dst = reinterpret_cast<f32x4*>(
            out + (size_t)(n * 512 + (y0 + py)) * 512 + (size_t)(x0 + px0));
        __builtin_nontemporal_store(ov, dst);
    }
}

extern "C" void kernel_launch(void* const* d_in, const int* in_sizes, int n_in,
                              void* d_out, int out_size, void* d_ws, size_t ws_size,
                              hipStream_t stream) {
    const float* in = (const float*)d_in[0];
    float* out = (float*)d_out;
    dim3 grid(512 / TILE_X, 512 / TILE_Y, 32);  // 8 x 16 x 32 = 4096 blocks
    dim3 block(TPB);
    lbp_kernel<<<grid, block, 0, stream>>>(in, out);
}